// Round 6
// baseline (41270.599 us; speedup 1.0000x reference)
//
#include <hip/hip_runtime.h>
#include <stdint.h>
#include <math.h>

#define BB 4096
#define HH 512
#define VV 32000
#define NT 15
#define STF 2097152   // BB*HH floats

struct KeysArg { uint32_t w[2*NT]; };

// JAX Threefry-2x32 (20 rounds, standard rotation/key schedule)
__host__ __device__ inline void tf2x32(uint32_t k0, uint32_t k1,
                                       uint32_t x0, uint32_t x1,
                                       uint32_t& o0, uint32_t& o1) {
  uint32_t ks2 = k0 ^ k1 ^ 0x1BD11BDAu;
  x0 += k0; x1 += k1;
#define TF_R(r) { x0 += x1; x1 = (x1 << (r)) | (x1 >> (32 - (r))); x1 ^= x0; }
  TF_R(13) TF_R(15) TF_R(26) TF_R(6)
  x0 += k1; x1 += ks2 + 1u;
  TF_R(17) TF_R(29) TF_R(16) TF_R(24)
  x0 += ks2; x1 += k0 + 2u;
  TF_R(13) TF_R(15) TF_R(26) TF_R(6)
  x0 += k0; x1 += k1 + 3u;
  TF_R(17) TF_R(29) TF_R(16) TF_R(24)
  x0 += k1; x1 += ks2 + 4u;
  TF_R(13) TF_R(15) TF_R(26) TF_R(6)
  x0 += ks2; x1 += k0 + 5u;
#undef TF_R
  o0 = x0; o1 = x1;
}

// 128x128x16-tile f32 GEMM, 256 threads, 8x8/thread, double-buffered LDS.
// Two parameter sets selected by blockIdx.z (split-K or split-operand);
// bias optional. One barrier per K-step; next tile's global loads issued
// before compute on current tile. VGPR capped via __launch_bounds__(256,3).
__global__ __launch_bounds__(256, 3)
void gemm_sk(const float* __restrict__ A0, int lda0,
             const float* __restrict__ W0, int koff0,
             const float* __restrict__ A1, int lda1,
             const float* __restrict__ W1, int koff1,
             int ldw, int Klen,
             const float* __restrict__ bias,
             float* __restrict__ C0, float* __restrict__ C1, int ldc)
{
  const float* A; const float* W; float* C; int lda, koff;
  if (blockIdx.z == 0) { A = A0; lda = lda0; W = W0; koff = koff0; C = C0; }
  else                 { A = A1; lda = lda1; W = W1; koff = koff1; C = C1; }

  __shared__ float As[2][16][128];
  __shared__ float Ws[2][16][128];
  const int tid = threadIdx.x;
  const int m0 = blockIdx.y * 128;
  const int n0 = blockIdx.x * 128;
  const int tx = tid & 15, ty = tid >> 4;
  float acc[8][8];
  #pragma unroll
  for (int i = 0; i < 8; ++i)
    #pragma unroll
    for (int j = 0; j < 8; ++j) acc[i][j] = 0.0f;

  const int sr = tid >> 1, sc = (tid & 1) * 8;   // A staging: row, k-col
  const int wk = tid >> 4, wn = (tid & 15) * 4;  // W staging: k-row, n-col

  float4 av0, av1, wv0, wv1;
  auto LOAD = [&](int kt) {
    const int k0 = koff + (kt << 4);
    const float* asrc = A + (size_t)(m0 + sr) * lda + (k0 + sc);
    av0 = *(const float4*)asrc;
    av1 = *(const float4*)(asrc + 4);
    const float* wsrc = W + (size_t)(k0 + wk) * ldw + (n0 + wn);
    wv0 = *(const float4*)wsrc;
    wv1 = *(const float4*)(wsrc + 64);
  };
  auto STORE = [&](int buf) {
    As[buf][sc+0][sr]=av0.x; As[buf][sc+1][sr]=av0.y;
    As[buf][sc+2][sr]=av0.z; As[buf][sc+3][sr]=av0.w;
    As[buf][sc+4][sr]=av1.x; As[buf][sc+5][sr]=av1.y;
    As[buf][sc+6][sr]=av1.z; As[buf][sc+7][sr]=av1.w;
    *(float4*)&Ws[buf][wk][wn]      = wv0;
    *(float4*)&Ws[buf][wk][wn + 64] = wv1;
  };

  LOAD(0);
  STORE(0);
  __syncthreads();

  const int nkt = Klen >> 4;
  int cur = 0;
  for (int kt = 0; kt < nkt; ++kt) {
    const bool more = (kt + 1 < nkt);
    if (more) LOAD(kt + 1);            // global loads in flight during compute
    #pragma unroll
    for (int kk = 0; kk < 16; ++kk) {
      float4 a0 = *(const float4*)&As[cur][kk][ty*8];
      float4 a1 = *(const float4*)&As[cur][kk][ty*8+4];
      float4 b0 = *(const float4*)&Ws[cur][kk][tx*4];
      float4 b1 = *(const float4*)&Ws[cur][kk][tx*4+64];
      float ar[8] = {a0.x,a0.y,a0.z,a0.w,a1.x,a1.y,a1.z,a1.w};
      float br[8] = {b0.x,b0.y,b0.z,b0.w,b1.x,b1.y,b1.z,b1.w};
      #pragma unroll
      for (int i = 0; i < 8; ++i)
        #pragma unroll
        for (int j = 0; j < 8; ++j)
          acc[i][j] = fmaf(ar[i], br[j], acc[i][j]);
    }
    if (more) {
      STORE(cur ^ 1);                  // other buffer: no barrier needed first
      __syncthreads();                 // publish before next iteration reads
    }
    cur ^= 1;
  }

  #pragma unroll
  for (int i = 0; i < 8; ++i) {
    const int m = m0 + ty*8 + i;
    float* dst = C + (size_t)m * ldc + (n0 + wn);
    float4 o0, o1;
    o0.x = acc[i][0]; o0.y = acc[i][1]; o0.z = acc[i][2]; o0.w = acc[i][3];
    o1.x = acc[i][4]; o1.y = acc[i][5]; o1.z = acc[i][6]; o1.w = acc[i][7];
    if (bias) {
      o0.x += bias[n0+wn+0]; o0.y += bias[n0+wn+1];
      o0.z += bias[n0+wn+2]; o0.w += bias[n0+wn+3];
      o1.x += bias[n0+wn+64]; o1.y += bias[n0+wn+65];
      o1.z += bias[n0+wn+66]; o1.w += bias[n0+wn+67];
    }
    *(float4*)dst        = o0;
    *(float4*)(dst + 64) = o1;
  }
}

// LSTM gate update from partial pre-activations: z = zx(opt) + z0 + z1 + bias
__global__ __launch_bounds__(256)
void gate_kernel(const float* __restrict__ zx, int zxs,
                 const float* __restrict__ z0, const float* __restrict__ z1,
                 const float* __restrict__ bias,
                 const float* __restrict__ cin,
                 float* __restrict__ hout, float* __restrict__ cout,
                 float* __restrict__ sh, float* __restrict__ sc)
{
  int idx = blockIdx.x * 256 + threadIdx.x;
  int b = idx >> 9, j = idx & 511;
  const size_t r2 = (size_t)b * 2048;
  float zi, zf, zg, zo;
  zi = z0[r2+j]      + z1[r2+j]      + bias[j];
  zf = z0[r2+j+512]  + z1[r2+j+512]  + bias[j+512];
  zg = z0[r2+j+1024] + z1[r2+j+1024] + bias[j+1024];
  zo = z0[r2+j+1536] + z1[r2+j+1536] + bias[j+1536];
  if (zx) {
    const size_t rx = (size_t)b * zxs;
    zi += zx[rx+j]; zf += zx[rx+j+512]; zg += zx[rx+j+1024]; zo += zx[rx+j+1536];
  }
  float si = 1.0f/(1.0f+expf(-zi));
  float sf = 1.0f/(1.0f+expf(-zf));
  float so = 1.0f/(1.0f+expf(-zo));
  float c = sf * cin[idx] + si * tanhf(zg);
  float h = so * tanhf(c);
  cout[idx] = c; hout[idx] = h;
  if (sh) { sh[idx] = h; sc[idx] = c; }
}

// per-row max, log-sum-exp, entropy (H = log s - w/s, w = sum (x-m)e^{x-m})
__global__ __launch_bounds__(256)
void rowstat_kernel(const float* __restrict__ logits,
                    float* __restrict__ rowM, float* __restrict__ rowLS,
                    float* __restrict__ rowEnt)
{
  const int row = blockIdx.x;
  const float* x = logits + (size_t)row * VV;
  const int tid = threadIdx.x;
  float m = -INFINITY;
  for (int v = tid; v < VV; v += 256) m = fmaxf(m, x[v]);
  #pragma unroll
  for (int off = 32; off; off >>= 1) m = fmaxf(m, __shfl_down(m, off));
  __shared__ float sm[4], ssum[4], swsum[4];
  if ((tid & 63) == 0) sm[tid >> 6] = m;
  __syncthreads();
  m = fmaxf(fmaxf(sm[0], sm[1]), fmaxf(sm[2], sm[3]));
  float s = 0.0f, w = 0.0f;
  for (int v = tid; v < VV; v += 256) {
    float d = x[v] - m;
    float e = expf(d);
    s += e; w += d * e;
  }
  #pragma unroll
  for (int off = 32; off; off >>= 1) { s += __shfl_down(s, off); w += __shfl_down(w, off); }
  if ((tid & 63) == 0) { ssum[tid >> 6] = s; swsum[tid >> 6] = w; }
  __syncthreads();
  if (tid == 0) {
    s = ssum[0]+ssum[1]+ssum[2]+ssum[3];
    w = swsum[0]+swsum[1]+swsum[2]+swsum[3];
    float ls = logf(s);
    rowM[row] = m; rowLS[row] = ls; rowEnt[row] = ls - w / s;
  }
}

// Partitionable-threefry Gumbel argmax, one block per row, 15 draws inner
// (round-2 proven structure: shared x[v] load + p across the 15 hashes).
// Element (b,v): counter p=b*VV+v, bits = o0^o1 of threefry(key_t, 0, p).
__global__ __launch_bounds__(256)
void sample_kernel(const float* __restrict__ logits,
                   const float* __restrict__ rowM, const float* __restrict__ rowLS,
                   const float* __restrict__ rowEnt,
                   float* __restrict__ out,
                   KeysArg keys, int bbase)
{
  const int l = blockIdx.x;
  const int b = bbase + l;
  const float* x = logits + (size_t)l * VV;
  const float m = rowM[l], ls = rowLS[l];

  float bv[NT];
  uint32_t bi[NT];
  #pragma unroll
  for (int t = 0; t < NT; ++t) { bv[t] = -INFINITY; bi[t] = 0; }

  const uint32_t pbase = (uint32_t)b * (uint32_t)VV;
  for (int v = threadIdx.x; v < VV; v += 256) {
    const float lp = (x[v] - m) - ls;   // JAX order: (x - max) - logsum
    const uint32_t p = pbase + (uint32_t)v;
    #pragma unroll
    for (int t = 0; t < NT; ++t) {
      uint32_t o0, o1;
      tf2x32(keys.w[2*t], keys.w[2*t+1], 0u, p, o0, o1);
      const uint32_t bits = o0 ^ o1;
      float u = fmaxf(__uint_as_float((bits >> 9) | 0x3f800000u) - 1.0f,
                      1.17549435e-38f);
      float g = -logf(-logf(u)) + lp;
      if (g > bv[t]) { bv[t] = g; bi[t] = (uint32_t)v; }
    }
  }

  __shared__ float rv[NT][4];
  __shared__ uint32_t ri[NT][4];
  const int lane = threadIdx.x & 63, wq = threadIdx.x >> 6;
  #pragma unroll
  for (int t = 0; t < NT; ++t) {
    float v = bv[t]; uint32_t idx = bi[t];
    #pragma unroll
    for (int off = 32; off; off >>= 1) {
      float ov = __shfl_down(v, off);
      uint32_t oi = __shfl_down(idx, off);
      if (ov > v || (ov == v && oi < idx)) { v = ov; idx = oi; }
    }
    if (lane == 0) { rv[t][wq] = v; ri[t][wq] = idx; }
  }
  __syncthreads();
  if (threadIdx.x < NT) {
    const int t = threadIdx.x;
    float v = rv[t][0]; uint32_t idx = ri[t][0];
    #pragma unroll
    for (int q = 1; q < 4; ++q) {
      float ov = rv[t][q]; uint32_t oi = ri[t][q];
      if (ov > v || (ov == v && oi < idx)) { v = ov; idx = oi; }
    }
    out[(size_t)b * 30 + t]      = (float)idx;              // message
    out[(size_t)b * 30 + 15 + t] = 0.0f;                    // message zero tail
    out[122880 + (size_t)t * BB + b] = (x[idx] - m) - ls;   // lp
    out[184320 + (size_t)t * BB + b] = rowEnt[l];           // ent
  }
}

extern "C" void kernel_launch(void* const* d_in, const int* in_sizes, int n_in,
                              void* d_out, int out_size, void* d_ws, size_t ws_size,
                              hipStream_t stream)
{
  const float* inp = (const float*)d_in[0];
  const float* Wx0 = (const float*)d_in[1];
  const float* Wh0 = (const float*)d_in[2];
  const float* b0v = (const float*)d_in[3];
  const float* Wx1 = (const float*)d_in[4];
  const float* Wh1 = (const float*)d_in[5];
  const float* b1v = (const float*)d_in[6];
  const float* Wd  = (const float*)d_in[7];
  const float* bdv = (const float*)d_in[8];
  float* out = (float*)d_out;
  float* ws = (float*)d_ws;

  // ws layout (floats): h0,c0,h1,c1 | rowM,rowLS,rowEnt | logits-region.
  // During the LSTM phase the logits region holds zxpre(16384x2048),
  // z0(4096x2048), z1(4096x2048) — overwritten by decode afterwards.
  float* h0 = ws;
  float* c0 = ws + (size_t)STF;
  float* h1 = ws + (size_t)2*STF;
  float* c1 = ws + (size_t)3*STF;
  float* rowM  = ws + (size_t)4*STF;
  float* rowLS = rowM + 4096;
  float* rowEnt = rowLS + 4096;
  float* logits = ws + (size_t)4*STF + 12288;
  float* zxpre = logits;                          // 33.6M floats
  float* z0 = zxpre + (size_t)16384*2048;         // 8.4M
  float* z1 = z0 + (size_t)4096*2048;             // 8.4M

  size_t ws_floats = ws_size / 4;
  size_t base = (size_t)4*STF + 12288;
  int CH = 4096;  // decoder rows per chunk
  while (CH > 128 && base + (size_t)CH*VV > ws_floats) CH >>= 1;

  hipMemsetAsync(ws, 0, (size_t)4*STF*sizeof(float), stream);  // zero states

  // Precompute Zx = inp_flat(16384x256) @ Wx0 (no bias)
  gemm_sk<<<dim3(2048/128, 16384/128, 1), 256, 0, stream>>>(
      inp, 256, Wx0, 0,  nullptr, 0, nullptr, 0,
      2048, 256, nullptr, zxpre, nullptr, 2048);

  for (int t = 0; t < 4; ++t) {
    // L0: h0 @ Wh0, K=512 split into two 256-halves (z-parts)
    gemm_sk<<<dim3(2048/128, 4096/128, 2), 256, 0, stream>>>(
        h0, 512, Wh0, 0,  h0, 512, Wh0, 256,
        2048, 256, nullptr, z0, z1, 2048);
    gate_kernel<<<STF/256, 256, 0, stream>>>(
        zxpre + t*2048, 8192, z0, z1, b0v, c0, h0, c0,
        (t==3) ? out + 245760 : (float*)nullptr,
        (t==3) ? out + 245760 + STF : (float*)nullptr);
    // L1: part0 = h0 @ Wx1, part1 = h1 @ Wh1 (each K=512)
    gemm_sk<<<dim3(2048/128, 4096/128, 2), 256, 0, stream>>>(
        h0, 512, Wx1, 0,  h1, 512, Wh1, 0,
        2048, 512, nullptr, z0, z1, 2048);
    gate_kernel<<<STF/256, 256, 0, stream>>>(
        nullptr, 0, z0, z1, b1v, c1, h1, c1, (float*)nullptr, (float*)nullptr);
  }

  // host-side partitionable (fold-like) split of key(42):
  // key_t = (o0, o1) = threefry((0,42), x0=0, x1=t)
  KeysArg ka;
  for (int t = 0; t < NT; ++t) {
    uint32_t o0, o1;
    tf2x32(0u, 42u, 0u, (uint32_t)t, o0, o1);
    ka.w[2*t] = o0; ka.w[2*t+1] = o1;
  }

  const int nch = 4096 / CH;
  for (int c = 0; c < nch; ++c) {
    int bbase = c * CH;
    gemm_sk<<<dim3(VV/128, CH/128, 1), 256, 0, stream>>>(
        h1 + (size_t)bbase*512, 512, Wd, 0,  nullptr, 0, nullptr, 0,
        VV, 512, bdv, logits, nullptr, VV);
    rowstat_kernel<<<CH, 256, 0, stream>>>(logits, rowM, rowLS, rowEnt);
    sample_kernel<<<CH, 256, 0, stream>>>(logits, rowM, rowLS, rowEnt, out, ka, bbase);
  }
}

// Round 7
// 7475.883 us; speedup vs baseline: 5.5205x; 5.5205x over previous
//
#include <hip/hip_runtime.h>
#include <stdint.h>
#include <math.h>

#define BB 4096
#define HH 512
#define VV 32000
#define NT 15
#define STF 2097152   // BB*HH floats

struct KeysArg { uint32_t w[2*NT]; };

// JAX Threefry-2x32 (20 rounds, standard rotation/key schedule)
__host__ __device__ inline void tf2x32(uint32_t k0, uint32_t k1,
                                       uint32_t x0, uint32_t x1,
                                       uint32_t& o0, uint32_t& o1) {
  uint32_t ks2 = k0 ^ k1 ^ 0x1BD11BDAu;
  x0 += k0; x1 += k1;
#define TF_R(r) { x0 += x1; x1 = (x1 << (r)) | (x1 >> (32 - (r))); x1 ^= x0; }
  TF_R(13) TF_R(15) TF_R(26) TF_R(6)
  x0 += k1; x1 += ks2 + 1u;
  TF_R(17) TF_R(29) TF_R(16) TF_R(24)
  x0 += ks2; x1 += k0 + 2u;
  TF_R(13) TF_R(15) TF_R(26) TF_R(6)
  x0 += k0; x1 += k1 + 3u;
  TF_R(17) TF_R(29) TF_R(16) TF_R(24)
  x0 += k1; x1 += ks2 + 4u;
  TF_R(13) TF_R(15) TF_R(26) TF_R(6)
  x0 += ks2; x1 += k0 + 5u;
#undef TF_R
  o0 = x0; o1 = x1;
}

// 128x128x16-tile f32 GEMM, 256 threads, 8x8/thread (R5 proven version).
// Two parameter sets selected by blockIdx.z; bias optional.
// NOTE: do NOT add a min-waves arg to launch_bounds — forcing VGPR<100
// caused scratch spills and 40x HBM overfetch (round-6 post-mortem).
__global__ __launch_bounds__(256)
void gemm_sk(const float* __restrict__ A0, int lda0,
             const float* __restrict__ W0, int koff0,
             const float* __restrict__ A1, int lda1,
             const float* __restrict__ W1, int koff1,
             int ldw, int Klen,
             const float* __restrict__ bias,
             float* __restrict__ C0, float* __restrict__ C1, int ldc)
{
  const float* A; const float* W; float* C; int lda, koff;
  if (blockIdx.z == 0) { A = A0; lda = lda0; W = W0; koff = koff0; C = C0; }
  else                 { A = A1; lda = lda1; W = W1; koff = koff1; C = C1; }

  __shared__ float As[16][128];
  __shared__ float Ws[16][128];
  const int tid = threadIdx.x;
  const int m0 = blockIdx.y * 128;
  const int n0 = blockIdx.x * 128;
  const int tx = tid & 15, ty = tid >> 4;
  float acc[8][8];
  #pragma unroll
  for (int i = 0; i < 8; ++i)
    #pragma unroll
    for (int j = 0; j < 8; ++j) acc[i][j] = 0.0f;

  const int sr = tid >> 1, sc = (tid & 1) * 8;   // A staging: row, k-col
  const int wk = tid >> 4, wn = (tid & 15) * 4;  // W staging: k-row, n-col

  const int nkt = Klen >> 4;
  for (int kt = 0; kt < nkt; ++kt) {
    const int k0 = koff + (kt << 4);
    const float* asrc = A + (size_t)(m0 + sr) * lda + (k0 + sc);
    float4 av0 = *(const float4*)asrc;
    float4 av1 = *(const float4*)(asrc + 4);
    const float* wsrc = W + (size_t)(k0 + wk) * ldw + (n0 + wn);
    float4 wv0 = *(const float4*)wsrc;
    float4 wv1 = *(const float4*)(wsrc + 64);
    As[sc+0][sr]=av0.x; As[sc+1][sr]=av0.y; As[sc+2][sr]=av0.z; As[sc+3][sr]=av0.w;
    As[sc+4][sr]=av1.x; As[sc+5][sr]=av1.y; As[sc+6][sr]=av1.z; As[sc+7][sr]=av1.w;
    *(float4*)&Ws[wk][wn]      = wv0;
    *(float4*)&Ws[wk][wn + 64] = wv1;
    __syncthreads();
    #pragma unroll
    for (int kk = 0; kk < 16; ++kk) {
      float4 a0 = *(const float4*)&As[kk][ty*8];
      float4 a1 = *(const float4*)&As[kk][ty*8+4];
      float4 b0 = *(const float4*)&Ws[kk][tx*4];
      float4 b1 = *(const float4*)&Ws[kk][tx*4+64];
      float ar[8] = {a0.x,a0.y,a0.z,a0.w,a1.x,a1.y,a1.z,a1.w};
      float br[8] = {b0.x,b0.y,b0.z,b0.w,b1.x,b1.y,b1.z,b1.w};
      #pragma unroll
      for (int i = 0; i < 8; ++i)
        #pragma unroll
        for (int j = 0; j < 8; ++j)
          acc[i][j] = fmaf(ar[i], br[j], acc[i][j]);
    }
    __syncthreads();
  }

  #pragma unroll
  for (int i = 0; i < 8; ++i) {
    const int m = m0 + ty*8 + i;
    float* dst = C + (size_t)m * ldc + (n0 + wn);
    float4 o0, o1;
    o0.x = acc[i][0]; o0.y = acc[i][1]; o0.z = acc[i][2]; o0.w = acc[i][3];
    o1.x = acc[i][4]; o1.y = acc[i][5]; o1.z = acc[i][6]; o1.w = acc[i][7];
    if (bias) {
      o0.x += bias[n0+wn+0]; o0.y += bias[n0+wn+1];
      o0.z += bias[n0+wn+2]; o0.w += bias[n0+wn+3];
      o1.x += bias[n0+wn+64]; o1.y += bias[n0+wn+65];
      o1.z += bias[n0+wn+66]; o1.w += bias[n0+wn+67];
    }
    *(float4*)dst        = o0;
    *(float4*)(dst + 64) = o1;
  }
}

// LSTM gate update from partial pre-activations: z = zx(opt) + z0 + z1 + bias
__global__ __launch_bounds__(256)
void gate_kernel(const float* __restrict__ zx, int zxs,
                 const float* __restrict__ z0, const float* __restrict__ z1,
                 const float* __restrict__ bias,
                 const float* __restrict__ cin,
                 float* __restrict__ hout, float* __restrict__ cout,
                 float* __restrict__ sh, float* __restrict__ sc)
{
  int idx = blockIdx.x * 256 + threadIdx.x;
  int b = idx >> 9, j = idx & 511;
  const size_t r2 = (size_t)b * 2048;
  float zi, zf, zg, zo;
  zi = z0[r2+j]      + z1[r2+j]      + bias[j];
  zf = z0[r2+j+512]  + z1[r2+j+512]  + bias[j+512];
  zg = z0[r2+j+1024] + z1[r2+j+1024] + bias[j+1024];
  zo = z0[r2+j+1536] + z1[r2+j+1536] + bias[j+1536];
  if (zx) {
    const size_t rx = (size_t)b * zxs;
    zi += zx[rx+j]; zf += zx[rx+j+512]; zg += zx[rx+j+1024]; zo += zx[rx+j+1536];
  }
  float si = 1.0f/(1.0f+expf(-zi));
  float sf = 1.0f/(1.0f+expf(-zf));
  float so = 1.0f/(1.0f+expf(-zo));
  float c = sf * cin[idx] + si * tanhf(zg);
  float h = so * tanhf(c);
  cout[idx] = c; hout[idx] = h;
  if (sh) { sh[idx] = h; sc[idx] = c; }
}

// per-row max, log-sum-exp, entropy (H = log s - w/s, w = sum (x-m)e^{x-m})
__global__ __launch_bounds__(256)
void rowstat_kernel(const float* __restrict__ logits,
                    float* __restrict__ rowM, float* __restrict__ rowLS,
                    float* __restrict__ rowEnt)
{
  const int row = blockIdx.x;
  const float* x = logits + (size_t)row * VV;
  const int tid = threadIdx.x;
  float m = -INFINITY;
  for (int v = tid; v < VV; v += 256) m = fmaxf(m, x[v]);
  #pragma unroll
  for (int off = 32; off; off >>= 1) m = fmaxf(m, __shfl_down(m, off));
  __shared__ float sm[4], ssum[4], swsum[4];
  if ((tid & 63) == 0) sm[tid >> 6] = m;
  __syncthreads();
  m = fmaxf(fmaxf(sm[0], sm[1]), fmaxf(sm[2], sm[3]));
  float s = 0.0f, w = 0.0f;
  for (int v = tid; v < VV; v += 256) {
    float d = x[v] - m;
    float e = expf(d);
    s += e; w += d * e;
  }
  #pragma unroll
  for (int off = 32; off; off >>= 1) { s += __shfl_down(s, off); w += __shfl_down(w, off); }
  if ((tid & 63) == 0) { ssum[tid >> 6] = s; swsum[tid >> 6] = w; }
  __syncthreads();
  if (tid == 0) {
    s = ssum[0]+ssum[1]+ssum[2]+ssum[3];
    w = swsum[0]+swsum[1]+swsum[2]+swsum[3];
    float ls = logf(s);
    rowM[row] = m; rowLS[row] = ls; rowEnt[row] = ls - w / s;
  }
}

// Partitionable-threefry Gumbel argmax, one block per row, 15 keys inner.
// Wave-uniform candidate filter: g = -log(-log(u)) is monotone in u, and
// lp <= lp_max = -ls exactly, so element (v,t) can only beat the wave's
// current best bv_wave[t] if uf >= thr[t], where thr[t] is derived from the
// WAVE max (shfl_xor reduce) with a conservative 0.999999 margin (round-4
// proven-safe logic). The __any() makes the branch wave-uniform: the 2x logf
// slow path is skipped entirely (s_cbranch_execz) for most (v,t).
// Skips only discard candidates that cannot exceed an earlier-indexed max,
// so the argmax and first-index tie-break are bit-identical.
__global__ __launch_bounds__(256)
void sample_kernel(const float* __restrict__ logits,
                   const float* __restrict__ rowM, const float* __restrict__ rowLS,
                   const float* __restrict__ rowEnt,
                   float* __restrict__ out,
                   KeysArg keys, int bbase)
{
  const int l = blockIdx.x;
  const int b = bbase + l;
  const float* x = logits + (size_t)l * VV;
  const float m = rowM[l], ls = rowLS[l];

  float bv[NT];
  uint32_t bi[NT];
  float thr[NT];
  #pragma unroll
  for (int t = 0; t < NT; ++t) { bv[t] = -INFINITY; bi[t] = 0; thr[t] = 1.0f; }

  const uint32_t pbase = (uint32_t)b * (uint32_t)VV;
  for (int v = threadIdx.x; v < VV; v += 256) {
    const float lp = (x[v] - m) - ls;   // JAX order: (x - max) - logsum
    const uint32_t p = pbase + (uint32_t)v;
    #pragma unroll
    for (int t = 0; t < NT; ++t) {
      uint32_t o0, o1;
      tf2x32(keys.w[2*t], keys.w[2*t+1], 0u, p, o0, o1);
      const uint32_t bits = o0 ^ o1;
      const float uf = __uint_as_float((bits >> 9) | 0x3f800000u);
      if (__any(uf >= thr[t])) {
        float u = fmaxf(uf - 1.0f, 1.17549435e-38f);
        float g = -logf(-logf(u)) + lp;
        bool improved = (uf >= thr[t]) && (g > bv[t]);
        if (improved) { bv[t] = g; bi[t] = (uint32_t)v; }
        if (__any(improved)) {
          // wave-shared threshold from wave-max of bv[t]
          float wb = bv[t];
          #pragma unroll
          for (int off = 1; off < 64; off <<= 1)
            wb = fmaxf(wb, __shfl_xor(wb, off));
          float us = expf(-expf(-(wb + ls)));
          thr[t] = 1.0f + us * 0.999999f;   // conservative: never false-skip
        }
      }
    }
  }

  __shared__ float rv[NT][4];
  __shared__ uint32_t ri[NT][4];
  const int lane = threadIdx.x & 63, wq = threadIdx.x >> 6;
  #pragma unroll
  for (int t = 0; t < NT; ++t) {
    float v = bv[t]; uint32_t idx = bi[t];
    #pragma unroll
    for (int off = 32; off; off >>= 1) {
      float ov = __shfl_down(v, off);
      uint32_t oi = __shfl_down(idx, off);
      if (ov > v || (ov == v && oi < idx)) { v = ov; idx = oi; }
    }
    if (lane == 0) { rv[t][wq] = v; ri[t][wq] = idx; }
  }
  __syncthreads();
  if (threadIdx.x < NT) {
    const int t = threadIdx.x;
    float v = rv[t][0]; uint32_t idx = ri[t][0];
    #pragma unroll
    for (int q = 1; q < 4; ++q) {
      float ov = rv[t][q]; uint32_t oi = ri[t][q];
      if (ov > v || (ov == v && oi < idx)) { v = ov; idx = oi; }
    }
    out[(size_t)b * 30 + t]      = (float)idx;              // message
    out[(size_t)b * 30 + 15 + t] = 0.0f;                    // message zero tail
    out[122880 + (size_t)t * BB + b] = (x[idx] - m) - ls;   // lp
    out[184320 + (size_t)t * BB + b] = rowEnt[l];           // ent
  }
}

extern "C" void kernel_launch(void* const* d_in, const int* in_sizes, int n_in,
                              void* d_out, int out_size, void* d_ws, size_t ws_size,
                              hipStream_t stream)
{
  const float* inp = (const float*)d_in[0];
  const float* Wx0 = (const float*)d_in[1];
  const float* Wh0 = (const float*)d_in[2];
  const float* b0v = (const float*)d_in[3];
  const float* Wx1 = (const float*)d_in[4];
  const float* Wh1 = (const float*)d_in[5];
  const float* b1v = (const float*)d_in[6];
  const float* Wd  = (const float*)d_in[7];
  const float* bdv = (const float*)d_in[8];
  float* out = (float*)d_out;
  float* ws = (float*)d_ws;

  // ws layout (floats): h0,c0,h1,c1 | rowM,rowLS,rowEnt | logits-region.
  // During the LSTM phase the logits region holds zxpre(16384x2048),
  // z0(4096x2048), z1(4096x2048) — overwritten by decode afterwards.
  float* h0 = ws;
  float* c0 = ws + (size_t)STF;
  float* h1 = ws + (size_t)2*STF;
  float* c1 = ws + (size_t)3*STF;
  float* rowM  = ws + (size_t)4*STF;
  float* rowLS = rowM + 4096;
  float* rowEnt = rowLS + 4096;
  float* logits = ws + (size_t)4*STF + 12288;
  float* zxpre = logits;                          // 33.6M floats
  float* z0 = zxpre + (size_t)16384*2048;         // 8.4M
  float* z1 = z0 + (size_t)4096*2048;             // 8.4M

  size_t ws_floats = ws_size / 4;
  size_t base = (size_t)4*STF + 12288;
  int CH = 4096;  // decoder rows per chunk
  while (CH > 128 && base + (size_t)CH*VV > ws_floats) CH >>= 1;

  hipMemsetAsync(ws, 0, (size_t)4*STF*sizeof(float), stream);  // zero states

  // Precompute Zx = inp_flat(16384x256) @ Wx0 (no bias)
  gemm_sk<<<dim3(2048/128, 16384/128, 1), 256, 0, stream>>>(
      inp, 256, Wx0, 0,  nullptr, 0, nullptr, 0,
      2048, 256, nullptr, zxpre, nullptr, 2048);

  for (int t = 0; t < 4; ++t) {
    // L0: h0 @ Wh0, K=512 split into two 256-halves (z-parts)
    gemm_sk<<<dim3(2048/128, 4096/128, 2), 256, 0, stream>>>(
        h0, 512, Wh0, 0,  h0, 512, Wh0, 256,
        2048, 256, nullptr, z0, z1, 2048);
    gate_kernel<<<STF/256, 256, 0, stream>>>(
        zxpre + t*2048, 8192, z0, z1, b0v, c0, h0, c0,
        (t==3) ? out + 245760 : (float*)nullptr,
        (t==3) ? out + 245760 + STF : (float*)nullptr);
    // L1: part0 = h0 @ Wx1, part1 = h1 @ Wh1 (each K=512)
    gemm_sk<<<dim3(2048/128, 4096/128, 2), 256, 0, stream>>>(
        h0, 512, Wx1, 0,  h1, 512, Wh1, 0,
        2048, 512, nullptr, z0, z1, 2048);
    gate_kernel<<<STF/256, 256, 0, stream>>>(
        nullptr, 0, z0, z1, b1v, c1, h1, c1, (float*)nullptr, (float*)nullptr);
  }

  // host-side partitionable (fold-like) split of key(42):
  // key_t = (o0, o1) = threefry((0,42), x0=0, x1=t)
  KeysArg ka;
  for (int t = 0; t < NT; ++t) {
    uint32_t o0, o1;
    tf2x32(0u, 42u, 0u, (uint32_t)t, o0, o1);
    ka.w[2*t] = o0; ka.w[2*t+1] = o1;
  }

  const int nch = 4096 / CH;
  for (int c = 0; c < nch; ++c) {
    int bbase = c * CH;
    gemm_sk<<<dim3(VV/128, CH/128, 1), 256, 0, stream>>>(
        h1 + (size_t)bbase*512, 512, Wd, 0,  nullptr, 0, nullptr, 0,
        VV, 512, bdv, logits, nullptr, VV);
    rowstat_kernel<<<CH, 256, 0, stream>>>(logits, rowM, rowLS, rowEnt);
    sample_kernel<<<CH, 256, 0, stream>>>(logits, rowM, rowLS, rowEnt, out, ka, bbase);
  }
}